// Round 14
// baseline (82.766 us; speedup 1.0000x reference)
//
#include <hip/hip_runtime.h>
#include <hip/hip_bf16.h>

#define M_DIM 4096
#define N_DIM 16384
#define K_DIM 256

typedef short short8 __attribute__((ext_vector_type(8)));
typedef float f32x4 __attribute__((ext_vector_type(4)));
typedef unsigned int u32x4 __attribute__((ext_vector_type(4)));

// fp32 -> bf16 (RNE) pack of two floats into one u32 (lo = first elem)
__device__ __forceinline__ unsigned int pk2bf(float lo, float hi) {
    unsigned int a = __float_as_uint(lo);
    unsigned int b = __float_as_uint(hi);
    a = (a + 0x7FFFu + ((a >> 16) & 1u)) >> 16;
    b = (b + 0x7FFFu + ((b >> 16) & 1u)) & 0xFFFF0000u;
    return a | b;
}

// ---------------------------------------------------------------------------
// Pre-pass (R12 version, unchanged): 1024 blocks.
//   blocks [0,512):    W -> Wt [N][K] bf16 (mask baked) via LDS transpose.
//   blocks [512,1024): x -> xb bf16 in MFMA-fragment-tiled layout (1 KB chunk
//                      per (mTile,kChunk); one A-frag load = one coalesced
//                      1 KB global_load_dwordx4).
// ---------------------------------------------------------------------------
__global__ __launch_bounds__(256) void convert_kernel(const float* __restrict__ W,
                                                      const float* __restrict__ x,
                                                      unsigned short* __restrict__ Wt,
                                                      unsigned short* __restrict__ xb) {
    const int bx = blockIdx.x;
    const int t  = threadIdx.x;
    if (bx < 512) {
        __shared__ unsigned short tile[128][64];   // 16 KB, XOR-swizzled rows
        const int n0  = (bx & 127) * 128;          // n-panel
        const int kc0 = (bx >> 7) * 64;            // k-chunk
        const int nn  = t & 127;                   // local n (row of tile)
        const int kh  = (t >> 7) * 32;             // k-half this thread fills
        const int jm  = (n0 + nn) >> 6;            // masked k for this n
        const int sw  = (nn & 7) << 3;             // XOR swizzle (8-elem granule)
        #pragma unroll
        for (int kk = 0; kk < 32; kk += 8) {
            float v[8];
            #pragma unroll
            for (int j = 0; j < 8; ++j) {
                const int k = kc0 + kh + kk + j;
                const float f = W[(size_t)k * N_DIM + n0 + nn];   // coalesced in n
                v[j] = (k == jm) ? 0.0f : f;
            }
            u32x4 p = { pk2bf(v[0], v[1]), pk2bf(v[2], v[3]),
                        pk2bf(v[4], v[5]), pk2bf(v[6], v[7]) };
            *(u32x4*)&tile[nn][(kh + kk) ^ sw] = p;
        }
        __syncthreads();
        const int kc = (t & 7) * 8;
        const int nr = t >> 3;
        #pragma unroll
        for (int it = 0; it < 4; ++it) {
            const int n = it * 32 + nr;
            u32x4 p = *(const u32x4*)&tile[n][kc ^ ((n & 7) << 3)];
            *(u32x4*)(Wt + (size_t)(n0 + n) * K_DIM + kc0 + kc) = p;
        }
    } else {
        const int g  = (bx - 512) * 256 + t;
        const int m  = g >> 5;
        const int k0 = (g & 31) * 8;
        const float4 a = *(const float4*)(x + (size_t)m * K_DIM + k0);
        const float4 b = *(const float4*)(x + (size_t)m * K_DIM + k0 + 4);
        u32x4 p = { pk2bf(a.x, a.y), pk2bf(a.z, a.w),
                    pk2bf(b.x, b.y), pk2bf(b.z, b.w) };
        const int chunk = (m >> 4) * 8 + (k0 >> 5);
        const int lane  = ((k0 & 31) >> 3) * 16 + (m & 15);
        ((u32x4*)xb)[chunk * 64 + lane] = p;
    }
}

// ---------------------------------------------------------------------------
// Main GEMM — single factor vs R13: tile aspect 128x128 -> 64x256.
// Block writes 1 KB per output row (vs 512 B) x 64 rows -> doubled DRAM page
// burst per row-visit (theory: residual 3.9-vs-6.9 TB/s write gap = page
// activation overhead of 512 B chunks at 64 KB stride). 4 waves each own a
// 64x64 slice (wm=0, wn=wave*64) -> MFMA/frag structure identical to R13.
// A-in-regs (fragment-tiled xb), Bs dbuf 64 KB (2 blocks/CU; R13 measured
// the 3rd block at only ~1.5 us), Cs = full-64KB alias, single-pass drain
// with 1 KB-contiguous wave store instructions. R9-banded map (8 tiles/XCD).
// ---------------------------------------------------------------------------
constexpr int BM = 64, BN = 256, BK = 64;

__global__ __launch_bounds__(256, 2) void gemm_kernel(
        const unsigned short* __restrict__ Abf,   // fragment-tiled bf16
        const unsigned short* __restrict__ Bbf,   // [N][K] bf16 (masked W^T)
        const float* __restrict__ bias,           // [N] f32
        float* __restrict__ out) {                // [M][N] f32
    __shared__ __align__(16) unsigned char smem[65536];
    auto Bs = (unsigned short (*)[BN][BK])(smem);   // 2 x 32 KB
    float* Cs = (float*)smem;                       // 64x256 f32 alias (64 KB)

    // R9-style banded map: XCD owns 8 contiguous n-tiles; n-fast within band.
    const int bid = blockIdx.x;                 // 4096 blocks (64 m x 64 n)
    const int xcd = bid & 7;
    const int q   = bid >> 3;                   // 0..511 per XCD
    const int n0  = (xcd * 8 + (q & 7)) * BN;
    const int m0  = (q >> 3) * BM;

    const int t    = threadIdx.x;
    const int lane = t & 63;
    const int wave = t >> 6;
    const int wn   = wave * 64;                 // wave's n-slice; wm = 0
    const int lr   = lane & 15;
    const int lk   = (lane >> 4) * 8;

    const int srow = t >> 3;                    // 0..31
    const int selk = (t & 7) * 8;

    // A: fragment-tiled chunks, shared by all 4 waves (L1-hit redundancy).
    const int mTB = m0 >> 4;
    const short8* gAt = (const short8*)Abf;     // 16 B units; chunk = 64 units

    const unsigned short* gB = Bbf + (size_t)(n0 + srow) * K_DIM + selk;

    u32x4 rb[8];
    auto ldregB = [&](int kt) {
        #pragma unroll
        for (int r = 0; r < 8; ++r)
            rb[r] = *(const u32x4*)(gB + (size_t)(r * 32) * K_DIM + kt * BK);
    };
    auto dswriteB = [&](int buf) {
        #pragma unroll
        for (int r = 0; r < 8; ++r) {
            const int row = srow + r * 32;
            const int c   = selk ^ ((row & 7) << 3);
            *(u32x4*)&Bs[buf][row][c] = rb[r];
        }
    };

    short8 afc[2][4], afn[2][4];   // A frags [ks][mi], current / next kt
    auto ldA = [&](short8 (&dst)[2][4], int kt) {
        #pragma unroll
        for (int ks = 0; ks < 2; ++ks)
            #pragma unroll
            for (int mi = 0; mi < 4; ++mi)
                dst[ks][mi] = gAt[(size_t)((mTB + mi) * 8 + kt * 2 + ks) * 64 + lane];
    };

    f32x4 acc[4][4] = {};

    ldA(afc, 0);
    ldregB(0);
    dswriteB(0);
    __syncthreads();

    #pragma unroll
    for (int kt = 0; kt < 4; ++kt) {
        const int buf = kt & 1;
        if (kt < 3) {
            ldA(afn, kt + 1);
            ldregB(kt + 1);
        }
        #pragma unroll
        for (int ks = 0; ks < 2; ++ks) {
            short8 bfr[4];
            #pragma unroll
            for (int ni = 0; ni < 4; ++ni) {
                const int row = wn + ni * 16 + lr;
                const int c   = (ks * 32 + lk) ^ ((row & 7) << 3);
                bfr[ni] = *(const short8*)&Bs[buf][row][c];
            }
            // Swapped operands: D[n][m] (verified R2): m=lane&15(+mi*16),
            // n=(lane>>4)*4+j(+ni*16)
            #pragma unroll
            for (int mi = 0; mi < 4; ++mi)
                #pragma unroll
                for (int ni = 0; ni < 4; ++ni)
                    acc[mi][ni] = __builtin_amdgcn_mfma_f32_16x16x32_bf16(
                        bfr[ni], afc[ks][mi], acc[mi][ni], 0, 0, 0);
        }
        if (kt < 3) {
            dswriteB(buf ^ 1);
            __syncthreads();
            #pragma unroll
            for (int ks = 0; ks < 2; ++ks)
                #pragma unroll
                for (int mi = 0; mi < 4; ++mi)
                    afc[ks][mi] = afn[ks][mi];
        }
    }

    // ---- epilogue: acc -> Cs[64][256] (swizzled) -> 1 KB-contiguous stores --
    __syncthreads();   // all waves done reading Bs before aliasing as Cs

    {
        const int nl0 = wn + (lane >> 4) * 4;
        #pragma unroll
        for (int mi = 0; mi < 4; ++mi) {
            const int rl = mi * 16 + lr;              // 0..63
            const int sx = (rl & 7) << 2;             // XOR swizzle, 4-float granule
            #pragma unroll
            for (int ni = 0; ni < 4; ++ni) {
                const int nl = (nl0 + ni * 16) ^ sx;
                *(f32x4*)&Cs[rl * BN + nl] = acc[mi][ni];
            }
        }
    }
    __syncthreads();

    {
        const int col4 = (t & 63) * 4;                // 0..252
        const float4 bv = *(const float4*)(bias + n0 + col4);
        #pragma unroll
        for (int p = 0; p < 16; ++p) {
            const int row = p * 4 + (t >> 6);         // 0..63
            const int cs  = col4 ^ ((row & 7) << 2);
            f32x4 v = *(const f32x4*)&Cs[row * BN + cs];
            v[0] += bv.x; v[1] += bv.y; v[2] += bv.z; v[3] += bv.w;
            *(f32x4*)(out + (size_t)(m0 + row) * N_DIM + n0 + col4) = v;
        }
    }
}

// ---------------------------------------------------------------------------
// Fallback (only if d_ws is too small): direct fp32, slow but correct.
// ---------------------------------------------------------------------------
__global__ __launch_bounds__(256) void fallback_kernel(const float* __restrict__ x,
                                                       const float* __restrict__ W,
                                                       const float* __restrict__ bias,
                                                       float* __restrict__ out) {
    const size_t gid = (size_t)blockIdx.x * 256 + threadIdx.x;
    const size_t row = gid / (N_DIM / 8);
    const int    c0  = (int)(gid % (N_DIM / 8)) * 8;
    const int    jm  = c0 >> 6;
    float acc[8] = {0, 0, 0, 0, 0, 0, 0, 0};
    const float* xr = x + row * K_DIM;
    for (int k = 0; k < K_DIM; ++k) {
        const float xv = (k == jm) ? 0.0f : xr[k];
        const float4* wr = (const float4*)(W + (size_t)k * N_DIM + c0);
        float4 w0 = wr[0], w1 = wr[1];
        acc[0] += xv * w0.x; acc[1] += xv * w0.y;
        acc[2] += xv * w0.z; acc[3] += xv * w0.w;
        acc[4] += xv * w1.x; acc[5] += xv * w1.y;
        acc[6] += xv * w1.z; acc[7] += xv * w1.w;
    }
    float* o = out + row * N_DIM + c0;
    #pragma unroll
    for (int j = 0; j < 8; ++j) o[j] = acc[j] + bias[c0 + j];
}

// ---------------------------------------------------------------------------
extern "C" void kernel_launch(void* const* d_in, const int* in_sizes, int n_in,
                              void* d_out, int out_size, void* d_ws, size_t ws_size,
                              hipStream_t stream) {
    const float* x    = (const float*)d_in[0];   // [4096, 256]
    const float* W    = (const float*)d_in[1];   // [256, 16384]
    const float* bias = (const float*)d_in[2];   // [16384]
    float* out        = (float*)d_out;           // [4096, 16384]

    const size_t wt_bytes = (size_t)N_DIM * K_DIM * 2;   // 8 MB
    const size_t xb_bytes = (size_t)M_DIM * K_DIM * 2;   // 2 MB

    if (ws_size >= wt_bytes + xb_bytes) {
        unsigned short* Wt = (unsigned short*)d_ws;
        unsigned short* xb = (unsigned short*)((char*)d_ws + wt_bytes);

        convert_kernel<<<512 + (M_DIM * K_DIM / 8) / 256, 256, 0, stream>>>(W, x, Wt, xb);
        gemm_kernel<<<(M_DIM / BM) * (N_DIM / BN), 256, 0, stream>>>(xb, Wt, bias, out);
    } else {
        const size_t total = (size_t)M_DIM * N_DIM / 8;
        fallback_kernel<<<(unsigned)(total / 256), 256, 0, stream>>>(x, W, bias, out);
    }
}

// Round 15
// 68.416 us; speedup vs baseline: 1.2097x; 1.2097x over previous
//
#include <hip/hip_runtime.h>
#include <hip/hip_bf16.h>

#define M_DIM 4096
#define N_DIM 16384
#define K_DIM 256

typedef short short8 __attribute__((ext_vector_type(8)));
typedef float f32x4 __attribute__((ext_vector_type(4)));
typedef unsigned int u32x4 __attribute__((ext_vector_type(4)));

// fp32 -> bf16 (RNE) pack of two floats into one u32 (lo = first elem)
__device__ __forceinline__ unsigned int pk2bf(float lo, float hi) {
    unsigned int a = __float_as_uint(lo);
    unsigned int b = __float_as_uint(hi);
    a = (a + 0x7FFFu + ((a >> 16) & 1u)) >> 16;
    b = (b + 0x7FFFu + ((b >> 16) & 1u)) & 0xFFFF0000u;
    return a | b;
}

// ---------------------------------------------------------------------------
// Pre-pass (R12 version, unchanged): 1024 blocks.
//   blocks [0,512):    W -> Wt [N][K] bf16 (mask baked) via LDS transpose.
//   blocks [512,1024): x -> xb bf16 in MFMA-fragment-tiled layout (1 KB chunk
//                      per (mTile,kChunk); one A-frag load = one coalesced
//                      1 KB global_load_dwordx4).
// ---------------------------------------------------------------------------
__global__ __launch_bounds__(256) void convert_kernel(const float* __restrict__ W,
                                                      const float* __restrict__ x,
                                                      unsigned short* __restrict__ Wt,
                                                      unsigned short* __restrict__ xb) {
    const int bx = blockIdx.x;
    const int t  = threadIdx.x;
    if (bx < 512) {
        __shared__ unsigned short tile[128][64];   // 16 KB, XOR-swizzled rows
        const int n0  = (bx & 127) * 128;          // n-panel
        const int kc0 = (bx >> 7) * 64;            // k-chunk
        const int nn  = t & 127;                   // local n (row of tile)
        const int kh  = (t >> 7) * 32;             // k-half this thread fills
        const int jm  = (n0 + nn) >> 6;            // masked k for this n
        const int sw  = (nn & 7) << 3;             // XOR swizzle (8-elem granule)
        #pragma unroll
        for (int kk = 0; kk < 32; kk += 8) {
            float v[8];
            #pragma unroll
            for (int j = 0; j < 8; ++j) {
                const int k = kc0 + kh + kk + j;
                const float f = W[(size_t)k * N_DIM + n0 + nn];   // coalesced in n
                v[j] = (k == jm) ? 0.0f : f;
            }
            u32x4 p = { pk2bf(v[0], v[1]), pk2bf(v[2], v[3]),
                        pk2bf(v[4], v[5]), pk2bf(v[6], v[7]) };
            *(u32x4*)&tile[nn][(kh + kk) ^ sw] = p;
        }
        __syncthreads();
        const int kc = (t & 7) * 8;
        const int nr = t >> 3;
        #pragma unroll
        for (int it = 0; it < 4; ++it) {
            const int n = it * 32 + nr;
            u32x4 p = *(const u32x4*)&tile[n][kc ^ ((n & 7) << 3)];
            *(u32x4*)(Wt + (size_t)(n0 + n) * K_DIM + kc0 + kc) = p;
        }
    } else {
        const int g  = (bx - 512) * 256 + t;
        const int m  = g >> 5;
        const int k0 = (g & 31) * 8;
        const float4 a = *(const float4*)(x + (size_t)m * K_DIM + k0);
        const float4 b = *(const float4*)(x + (size_t)m * K_DIM + k0 + 4);
        u32x4 p = { pk2bf(a.x, a.y), pk2bf(a.z, a.w),
                    pk2bf(b.x, b.y), pk2bf(b.z, b.w) };
        const int chunk = (m >> 4) * 8 + (k0 >> 5);
        const int lane  = ((k0 & 31) >> 3) * 16 + (m & 15);
        ((u32x4*)xb)[chunk * 64 + lane] = p;
    }
}

// ---------------------------------------------------------------------------
// Main GEMM — R13 byte-identical EXCEPT single factor: the drain-loop global
// stores are NONTEMPORAL. Theory: stores land in L2 (write-back) and dirty
// lines from ~64 interleaved tiles evict to HBM in near-arbitrary order ->
// DRAM write stream is shuffled 128 B lines (page locality destroyed), which
// is why every CU-side lever saturates at ~3.9 TB/s while streaming fills do
// 6.9. R13's drain stores are ALIGNED 512 B per instruction (above the HBM
// burst granule), so NT now delivers in-order full bursts (R2's NT disaster
// was 64 B fragments -> partial bursts). Also frees L2 for the B band.
// ---------------------------------------------------------------------------
constexpr int BM = 128, BN = 128, BK = 64;

__global__ __launch_bounds__(256, 3) void gemm_kernel(
        const unsigned short* __restrict__ Abf,   // fragment-tiled bf16
        const unsigned short* __restrict__ Bbf,   // [N][K] bf16 (masked W^T)
        const float* __restrict__ bias,           // [N] f32
        float* __restrict__ out) {                // [M][N] f32
    __shared__ __align__(16) unsigned char smem[32768];
    auto Bs = (unsigned short (*)[BN][BK])(smem);   // 2 x 16 KB
    float* Cs2 = (float*)smem;                      // 64x128 f32 alias (32 KB)

    // R9 mapping: XCD keeps a contiguous 16-tile n-band; n-fast within band.
    const int bid = blockIdx.x;
    const int xcd = bid & 7;
    const int q   = bid >> 3;
    const int n0  = (xcd * 16 + (q & 15)) * BN;
    const int m0  = (q >> 4) * BM;

    const int t    = threadIdx.x;
    const int lane = t & 63;
    const int wave = t >> 6;
    const int wm   = (wave >> 1) * 64;
    const int wn   = (wave & 1) * 64;
    const int lr   = lane & 15;
    const int lk   = (lane >> 4) * 8;

    const int srow = t >> 3;
    const int selk = (t & 7) * 8;

    // A: fragment-tiled chunks. Wave's m-tiles: mTB+mi (mi=0..3).
    const int mTB = (m0 + wm) >> 4;
    const short8* gAt = (const short8*)Abf;   // 16 B units; chunk = 64 units

    const unsigned short* gB = Bbf + (size_t)(n0 + srow) * K_DIM + selk;

    u32x4 rb[4];
    auto ldregB = [&](int kt) {
        #pragma unroll
        for (int r = 0; r < 4; ++r)
            rb[r] = *(const u32x4*)(gB + (size_t)(r * 32) * K_DIM + kt * BK);
    };
    auto dswriteB = [&](int buf) {
        #pragma unroll
        for (int r = 0; r < 4; ++r) {
            const int row = srow + r * 32;
            const int c   = selk ^ ((row & 7) << 3);
            *(u32x4*)&Bs[buf][row][c] = rb[r];
        }
    };

    short8 afc[2][4], afn[2][4];   // A frags [ks][mi], current / next kt
    auto ldA = [&](short8 (&dst)[2][4], int kt) {
        #pragma unroll
        for (int ks = 0; ks < 2; ++ks)
            #pragma unroll
            for (int mi = 0; mi < 4; ++mi)
                dst[ks][mi] = gAt[(size_t)((mTB + mi) * 8 + kt * 2 + ks) * 64 + lane];
    };

    f32x4 acc[4][4] = {};

    ldA(afc, 0);
    ldregB(0);
    dswriteB(0);
    __syncthreads();

    #pragma unroll
    for (int kt = 0; kt < 4; ++kt) {
        const int buf = kt & 1;
        if (kt < 3) {
            ldA(afn, kt + 1);      // coalesced 1 KB loads, fly under MFMA
            ldregB(kt + 1);
        }
        #pragma unroll
        for (int ks = 0; ks < 2; ++ks) {
            short8 bfr[4];
            #pragma unroll
            for (int ni = 0; ni < 4; ++ni) {
                const int row = wn + ni * 16 + lr;
                const int c   = (ks * 32 + lk) ^ ((row & 7) << 3);
                bfr[ni] = *(const short8*)&Bs[buf][row][c];
            }
            // Swapped operands: D[n][m] (verified R2): m=lane&15(+mi*16),
            // n=(lane>>4)*4+j(+ni*16)
            #pragma unroll
            for (int mi = 0; mi < 4; ++mi)
                #pragma unroll
                for (int ni = 0; ni < 4; ++ni)
                    acc[mi][ni] = __builtin_amdgcn_mfma_f32_16x16x32_bf16(
                        bfr[ni], afc[ks][mi], acc[mi][ni], 0, 0, 0);
        }
        if (kt < 3) {
            dswriteB(buf ^ 1);
            __syncthreads();
            #pragma unroll
            for (int ks = 0; ks < 2; ++ks)
                #pragma unroll
                for (int mi = 0; mi < 4; ++mi)
                    afc[ks][mi] = afn[ks][mi];
        }
    }

    // ---- two-pass epilogue through 32 KB Cs half-tile (NT drain stores) ----
    __syncthreads();   // all waves done reading Bs before aliasing as Cs2

    const int halfSel = wave >> 1;            // 0: rows 0..63, 1: rows 64..127
    const int col4 = (t & 31) * 4;
    const float4 bv = *(const float4*)(bias + n0 + col4);

    #pragma unroll
    for (int h = 0; h < 2; ++h) {
        if (halfSel == h) {
            const int nl0 = wn + (lane >> 4) * 4;
            #pragma unroll
            for (int mi = 0; mi < 4; ++mi) {
                const int rl = mi * 16 + lr;          // 0..63
                const int sx = (rl & 7) << 2;
                #pragma unroll
                for (int ni = 0; ni < 4; ++ni) {
                    const int nl = (nl0 + ni * 16) ^ sx;
                    *(f32x4*)&Cs2[rl * BN + nl] = acc[mi][ni];
                }
            }
        }
        __syncthreads();
        #pragma unroll
        for (int p = 0; p < 8; ++p) {
            const int row = p * 8 + (t >> 5);         // 0..63
            const int cs  = col4 ^ ((row & 7) << 2);
            f32x4 v = *(const f32x4*)&Cs2[row * BN + cs];
            v[0] += bv.x; v[1] += bv.y; v[2] += bv.z; v[3] += bv.w;
            __builtin_nontemporal_store(v,
                (f32x4*)(out + (size_t)(m0 + h * 64 + row) * N_DIM + n0 + col4));
        }
        if (h == 0) __syncthreads();   // drain reads before pass-1 writes
    }
}

// ---------------------------------------------------------------------------
// Fallback (only if d_ws is too small): direct fp32, slow but correct.
// ---------------------------------------------------------------------------
__global__ __launch_bounds__(256) void fallback_kernel(const float* __restrict__ x,
                                                       const float* __restrict__ W,
                                                       const float* __restrict__ bias,
                                                       float* __restrict__ out) {
    const size_t gid = (size_t)blockIdx.x * 256 + threadIdx.x;
    const size_t row = gid / (N_DIM / 8);
    const int    c0  = (int)(gid % (N_DIM / 8)) * 8;
    const int    jm  = c0 >> 6;
    float acc[8] = {0, 0, 0, 0, 0, 0, 0, 0};
    const float* xr = x + row * K_DIM;
    for (int k = 0; k < K_DIM; ++k) {
        const float xv = (k == jm) ? 0.0f : xr[k];
        const float4* wr = (const float4*)(W + (size_t)k * N_DIM + c0);
        float4 w0 = wr[0], w1 = wr[1];
        acc[0] += xv * w0.x; acc[1] += xv * w0.y;
        acc[2] += xv * w0.z; acc[3] += xv * w0.w;
        acc[4] += xv * w1.x; acc[5] += xv * w1.y;
        acc[6] += xv * w1.z; acc[7] += xv * w1.w;
    }
    float* o = out + row * N_DIM + c0;
    #pragma unroll
    for (int j = 0; j < 8; ++j) o[j] = acc[j] + bias[c0 + j];
}

// ---------------------------------------------------------------------------
extern "C" void kernel_launch(void* const* d_in, const int* in_sizes, int n_in,
                              void* d_out, int out_size, void* d_ws, size_t ws_size,
                              hipStream_t stream) {
    const float* x    = (const float*)d_in[0];   // [4096, 256]
    const float* W    = (const float*)d_in[1];   // [256, 16384]
    const float* bias = (const float*)d_in[2];   // [16384]
    float* out        = (float*)d_out;           // [4096, 16384]

    const size_t wt_bytes = (size_t)N_DIM * K_DIM * 2;   // 8 MB
    const size_t xb_bytes = (size_t)M_DIM * K_DIM * 2;   // 2 MB

    if (ws_size >= wt_bytes + xb_bytes) {
        unsigned short* Wt = (unsigned short*)d_ws;
        unsigned short* xb = (unsigned short*)((char*)d_ws + wt_bytes);

        convert_kernel<<<512 + (M_DIM * K_DIM / 8) / 256, 256, 0, stream>>>(W, x, Wt, xb);
        gemm_kernel<<<(M_DIM / BM) * (N_DIM / BN), 256, 0, stream>>>(xb, Wt, bias, out);
    } else {
        const size_t total = (size_t)M_DIM * N_DIM / 8;
        fallback_kernel<<<(unsigned)(total / 256), 256, 0, stream>>>(x, W, bias, out);
    }
}